// Round 7
// baseline (169.319 us; speedup 1.0000x reference)
//
#include <hip/hip_runtime.h>
#include <hip/hip_bf16.h>

// ---------------------------------------------------------------------------
// advantage = -0.5 * || T(flat) @ (actions-best) ||^2 per row, where
// flat = logits @ W^T + b, T = lower-tri scatter with squared diagonal.
// Round 7: N split into 2 column-blocks (272 cols each) -> acc 80 regs,
// LDS 41 KB -> 3 blocks/CU (12 waves/CU). W via glds dbuf; A global->reg
// (L1-served). Partial tril-matvec per half -> ws; tiny reduce kernel sums.
// ---------------------------------------------------------------------------

typedef __attribute__((ext_vector_type(8))) __bf16 bf16x8;
typedef __attribute__((ext_vector_type(4))) float f32x4;

#define AS1 __attribute__((address_space(1)))
#define AS3 __attribute__((address_space(3)))

__device__ __forceinline__ unsigned short f2b(float x) {
  unsigned u = __builtin_bit_cast(unsigned, x);
  u += 0x7fffu + ((u >> 16) & 1u);     // RNE; inputs are finite
  return (unsigned short)(u >> 16);
}
__device__ __forceinline__ float b2f(unsigned short h) {
  unsigned u = ((unsigned)h) << 16;
  return __builtin_bit_cast(float, u);
}

#define NFRAG 34                       // 544 padded cols / 16 (WP layout)
#define WK_BYTES (NFRAG * 1024)        // 34816 B per BK=32 k-step in WP
#define WSTEP 17408                    // 17 frags * 1024 (one col-half, one step)
#define FL2_STRIDE 640                 // flat-half row stride (544 data + pad, x128)
#define SMEM_BYTES 40960               // max(2*WSTEP=34816, 64*640=40960)
#define WS2_OFF 557056                 // f32 partials after WP in d_ws

// --- prep: W [528][512] f32 -> fragment-linear bf16, padded to 544 rows ----
// WP[k16][nf][lane][j] = bf16(W[nf*16+(lane&15)][k16*32+(lane>>4)*8+j])
__global__ void prep_wp(const float* __restrict__ W, unsigned short* __restrict__ WP) {
  int t = blockIdx.x * 256 + threadIdx.x;   // [0, 34816)
  int lane = t & 63;
  int u = t >> 6;                            // [0, 544)
  int nf = u % NFRAG;
  int k16 = u / NFRAG;                       // [0, 16)
  int n = nf * 16 + (lane & 15);
  int k0 = k16 * 32 + (lane >> 4) * 8;
  unsigned short h[8];
  if (n < 528) {
    const float* src = W + (size_t)n * 512 + k0;
#pragma unroll
    for (int j = 0; j < 8; ++j) h[j] = f2b(src[j]);
  } else {
#pragma unroll
    for (int j = 0; j < 8; ++j) h[j] = 0;
  }
  uint4 p;
  p.x = (unsigned)h[0] | ((unsigned)h[1] << 16);
  p.y = (unsigned)h[2] | ((unsigned)h[3] << 16);
  p.z = (unsigned)h[4] | ((unsigned)h[5] << 16);
  p.w = (unsigned)h[6] | ((unsigned)h[7] << 16);
  *(uint4*)(WP + (size_t)t * 8) = p;
}

// --- partial tril matvec over flat cols [LO, LO+272); i in {IT, IT+4, ...} -
template <int IT, int LO>
__device__ __forceinline__ void epi_partial2(const char* smem,
                                             const float* __restrict__ actions,
                                             const float* __restrict__ best,
                                             int grow, int lrow, float* pv) {
  float d[32];
  const float* ap = actions + (size_t)grow * 32;
  const float* bp = best + (size_t)grow * 32;
#pragma unroll
  for (int q = 0; q < 8; ++q) {
    float4 av = *(const float4*)(ap + q * 4);
    float4 bv = *(const float4*)(bp + q * 4);
    d[q * 4 + 0] = av.x - bv.x;
    d[q * 4 + 1] = av.y - bv.y;
    d[q * 4 + 2] = av.z - bv.z;
    d[q * 4 + 3] = av.w - bv.w;
  }
  const char* frow = smem + lrow * FL2_STRIDE;
  const int swz = (lrow & 7) << 4;
#pragma unroll
  for (int ii = 0; ii < 8; ++ii) {
    const int i = IT + ii * 4;                    // compile-time
    const int tri = (i * (i + 1)) >> 1;
    const int jlo = (LO > tri) ? (LO - tri) : 0;
    const int jhi = (i < LO + 271 - tri) ? i : (LO + 271 - tri);
    float vec = 0.f;
    if (jlo <= jhi) {                             // compile-time prune
      const int s0 = ((tri + jlo - LO) * 2) >> 4;
      const int s1 = ((tri + jhi - LO) * 2) >> 4;
#pragma unroll
      for (int s = s0; s <= s1; ++s) {
        uint4 w = *(const uint4*)(frow + ((s * 16) ^ swz));
        const unsigned* wp = (const unsigned*)&w;
#pragma unroll
        for (int e = 0; e < 8; ++e) {
          const int j = s * 8 + e + LO - tri;     // compile-time
          if (j < jlo || j > jhi) continue;
          unsigned short h = (e & 1) ? (unsigned short)(wp[e >> 1] >> 16)
                                     : (unsigned short)(wp[e >> 1] & 0xffffu);
          float v = b2f(h);
          if (j == i) vec += v * v * d[i];        // squared diagonal
          else        vec += v * d[j];
        }
      }
    }
    pv[ii] = vec;                                 // partial (NOT squared)
  }
}

// --- main fused kernel ------------------------------------------------------
__global__ void __launch_bounds__(256, 3)
adv_kernel(const float* __restrict__ logits,
           const float* __restrict__ best,
           const float* __restrict__ actions,
           const float* __restrict__ bvec,
           const unsigned short* __restrict__ WP,
           float* __restrict__ ws2) {
  extern __shared__ char smem[];
  const int tid = threadIdx.x;
  const int l   = tid & 63;
  const int wid = tid >> 6;                // 4 waves = 4 N-subcols of the half
  const int lr  = l & 15;
  const int lg  = l >> 4;
  const int c      = blockIdx.x & 1;       // column half: 0 -> cols 0..271
  const int brow   = (blockIdx.x >> 1) * 64;
  const int cstart = c * 17;               // first frag of this half
  const int startr = wid * 4;              // relative frag start (0,4,8,12)

  f32x4 acc[4][5];                         // 80 VGPRs
  {
    f32x4 zero = {0.f, 0.f, 0.f, 0.f};
#pragma unroll
    for (int m = 0; m < 4; ++m)
#pragma unroll
      for (int n = 0; n < 5; ++n) acc[m][n] = zero;
  }

#define STAGE_W(dst, ks)                                                        \
  {                                                                             \
    const char* sW = (const char*)WP + (size_t)(ks) * WK_BYTES +                \
                     (size_t)cstart * 1024;                                     \
    _Pragma("unroll")                                                           \
    for (int q = 0; q < 4; ++q) {                                               \
      int fr = wid + q * 4;                                                     \
      __builtin_amdgcn_global_load_lds(                                         \
          (AS1 unsigned int*)(sW + fr * 1024 + l * 16),                         \
          (AS3 unsigned int*)((dst) + fr * 1024 + l * 16), 16, 0, 0);           \
    }                                                                           \
    if (wid == 0)                                                               \
      __builtin_amdgcn_global_load_lds(                                         \
          (AS1 unsigned int*)(sW + 16 * 1024 + l * 16),                         \
          (AS3 unsigned int*)((dst) + 16 * 1024 + l * 16), 16, 0, 0);           \
  }

  // A: global f32 -> bf16 pack in-register; 8 KB/step tile is L1-resident so
  // the 4-wave redundancy is served by L1, not LDS.
#define COMPUTE(p, t)                                                           \
  {                                                                             \
    const char* wb = smem + (p) * WSTEP;                                        \
    f32x4 x[4][2];                                                              \
    _Pragma("unroll")                                                           \
    for (int m = 0; m < 4; ++m) {                                               \
      const float* g = logits + (size_t)(brow + m * 16 + lr) * 512 +            \
                       (t) * 32 + lg * 8;                                       \
      x[m][0] = *(const f32x4*)(g);                                             \
      x[m][1] = *(const f32x4*)(g + 4);                                         \
    }                                                                           \
    bf16x8 a[4];                                                                \
    _Pragma("unroll")                                                           \
    for (int m = 0; m < 4; ++m) {                                               \
      bf16x8 af;                                                                \
      af[0] = (__bf16)x[m][0][0]; af[1] = (__bf16)x[m][0][1];                   \
      af[2] = (__bf16)x[m][0][2]; af[3] = (__bf16)x[m][0][3];                   \
      af[4] = (__bf16)x[m][1][0]; af[5] = (__bf16)x[m][1][1];                   \
      af[6] = (__bf16)x[m][1][2]; af[7] = (__bf16)x[m][1][3];                   \
      a[m] = af;                                                                \
    }                                                                           \
    _Pragma("unroll")                                                           \
    for (int n = 0; n < 5; ++n) {                                               \
      bf16x8 w = *(const bf16x8*)(wb + (startr + n) * 1024 + l * 16);           \
      _Pragma("unroll")                                                         \
      for (int m = 0; m < 4; ++m)                                               \
        acc[m][n] = __builtin_amdgcn_mfma_f32_16x16x32_bf16(a[m], w, acc[m][n], 0, 0, 0); \
    }                                                                           \
  }

  STAGE_W(smem, 0)
  __syncthreads();

  for (int t2 = 0; t2 < 16; t2 += 2) {
    if (t2 < 15) STAGE_W(smem + WSTEP, t2 + 1)
    COMPUTE(0, t2)
    __syncthreads();
    if (t2 + 2 < 16) STAGE_W(smem, t2 + 2)
    COMPUTE(1, t2 + 1)
    __syncthreads();
  }

  // ---- flat-half(+bias) -> swizzled bf16 LDS [64][FL2_STRIDE] --------------
#pragma unroll
  for (int n = 0; n < 5; ++n) {
    int f_rel = (startr + n) * 16 + lr;    // < 272 always
    int f_abs = c * 272 + f_rel;
    if (f_abs < 528) {                     // frag 33 (pad) skipped
      float bb = bvec[f_abs];
#pragma unroll
      for (int m = 0; m < 4; ++m)
#pragma unroll
        for (int r = 0; r < 4; ++r) {
          int row = m * 16 + lg * 4 + r;   // C/D: col=lane&15, row=(lane>>4)*4+reg
          int byte = row * FL2_STRIDE + ((f_rel * 2) ^ ((row & 7) << 4));
          *(unsigned short*)(smem + byte) = f2b(acc[m][n][r] + bb);
        }
    }
  }
  __syncthreads();

  // ---- partial tril matvec: 4 thr/row, i = it + 4*ii; store to ws ----------
  {
    int it  = tid & 3;
    int lrow = tid >> 2;
    int grow = brow + lrow;
    float pv[8];
    if (c == 0) {
      switch (it) {
        case 0:  epi_partial2<0, 0>(smem, actions, best, grow, lrow, pv); break;
        case 1:  epi_partial2<1, 0>(smem, actions, best, grow, lrow, pv); break;
        case 2:  epi_partial2<2, 0>(smem, actions, best, grow, lrow, pv); break;
        default: epi_partial2<3, 0>(smem, actions, best, grow, lrow, pv); break;
      }
    } else {
      switch (it) {
        case 0:  epi_partial2<0, 272>(smem, actions, best, grow, lrow, pv); break;
        case 1:  epi_partial2<1, 272>(smem, actions, best, grow, lrow, pv); break;
        case 2:  epi_partial2<2, 272>(smem, actions, best, grow, lrow, pv); break;
        default: epi_partial2<3, 272>(smem, actions, best, grow, lrow, pv); break;
      }
    }
    float* wsp = ws2 + (size_t)grow * 64 + c * 32 + it * 8;
    float4 v0 = {pv[0], pv[1], pv[2], pv[3]};
    float4 v1 = {pv[4], pv[5], pv[6], pv[7]};
    *(float4*)(wsp)     = v0;
    *(float4*)(wsp + 4) = v1;
  }
}

// --- reduce: vec = half0 + half1; out = -0.5 * sum(vec^2) -------------------
__global__ void __launch_bounds__(256)
reduce_k(const float* __restrict__ ws2, float* __restrict__ out) {
  int row = blockIdx.x * 256 + threadIdx.x;
  const float* p = ws2 + (size_t)row * 64;
  float v[64];
#pragma unroll
  for (int q = 0; q < 16; ++q) {
    float4 x = *(const float4*)(p + q * 4);
    v[q * 4 + 0] = x.x; v[q * 4 + 1] = x.y; v[q * 4 + 2] = x.z; v[q * 4 + 3] = x.w;
  }
  float ssum = 0.f;
#pragma unroll
  for (int i = 0; i < 32; ++i) {
    int it = i & 3, ii = i >> 2;
    float vec = v[it * 8 + ii] + v[32 + it * 8 + ii];   // [c][it][ii]
    ssum += vec * vec;
  }
  out[row] = -0.5f * ssum;
}

extern "C" void kernel_launch(void* const* d_in, const int* in_sizes, int n_in,
                              void* d_out, int out_size, void* d_ws, size_t ws_size,
                              hipStream_t stream) {
  const float* logits  = (const float*)d_in[0];
  const float* best    = (const float*)d_in[1];
  const float* actions = (const float*)d_in[2];
  const float* W       = (const float*)d_in[3];
  const float* bvec    = (const float*)d_in[4];
  float* out = (float*)d_out;
  unsigned short* WP = (unsigned short*)d_ws;                 // 557056 B
  float* ws2 = (float*)((char*)d_ws + WS2_OFF);               // 65536*64*4 B

  hipLaunchKernelGGL(prep_wp, dim3(136), dim3(256), 0, stream, W, WP);
  int M = in_sizes[0] / 512;                                  // 65536 rows
  hipLaunchKernelGGL(adv_kernel, dim3((M / 64) * 2), dim3(256), SMEM_BYTES,
                     stream, logits, best, actions, bvec, WP, ws2);
  hipLaunchKernelGGL(reduce_k, dim3(M / 256), dim3(256), 0, stream, ws2, out);
}

// Round 8
// 90.401 us; speedup vs baseline: 1.8730x; 1.8730x over previous
//
#include <hip/hip_runtime.h>
#include <hip/hip_bf16.h>

// ---------------------------------------------------------------------------
// advantage = -0.5 * || T(flat) @ (actions-best) ||^2 per row, where
// flat = logits @ W^T + b, T = lower-tri scatter with squared diagonal.
// Round 8: round-7 N-split skeleton (2 column-halves, acc=80 regs, 3 blk/CU,
// partials->ws + reduce kernel) + round-4 A-path (distance-2 reg prefetch,
// collective 4KB bf16 frag-image staging, linear conflict-free LDS).
// ---------------------------------------------------------------------------

typedef __attribute__((ext_vector_type(8))) __bf16 bf16x8;
typedef __attribute__((ext_vector_type(4))) float f32x4;

#define AS1 __attribute__((address_space(1)))
#define AS3 __attribute__((address_space(3)))

__device__ __forceinline__ unsigned short f2b(float x) {
  unsigned u = __builtin_bit_cast(unsigned, x);
  u += 0x7fffu + ((u >> 16) & 1u);     // RNE; inputs are finite
  return (unsigned short)(u >> 16);
}
__device__ __forceinline__ float b2f(unsigned short h) {
  unsigned u = ((unsigned)h) << 16;
  return __builtin_bit_cast(float, u);
}

#define NFRAG 34                       // 544 padded cols / 16 (WP layout)
#define WK_BYTES (NFRAG * 1024)        // 34816 B per BK=32 k-step in WP
#define WSTEP 17408                    // 17 frags * 1024 (one col-half, one step)
#define AOFF (2 * WSTEP)               // 34816: A bufs (2 x 4096 bf16 frag-image)
#define SMEM_BYTES (AOFF + 2 * 4096)   // 43008 -> 3 blocks/CU; epi 40960 fits
#define FL2_STRIDE 640                 // flat-half row stride (bytes)
#define WS2_OFF 557056                 // f32 partials after WP in d_ws

// --- prep: W [528][512] f32 -> fragment-linear bf16, padded to 544 rows ----
// WP[k16][nf][lane][j] = bf16(W[nf*16+(lane&15)][k16*32+(lane>>4)*8+j])
__global__ void prep_wp(const float* __restrict__ W, unsigned short* __restrict__ WP) {
  int t = blockIdx.x * 256 + threadIdx.x;   // [0, 34816)
  int lane = t & 63;
  int u = t >> 6;                            // [0, 544)
  int nf = u % NFRAG;
  int k16 = u / NFRAG;                       // [0, 16)
  int n = nf * 16 + (lane & 15);
  int k0 = k16 * 32 + (lane >> 4) * 8;
  unsigned short h[8];
  if (n < 528) {
    const float* src = W + (size_t)n * 512 + k0;
#pragma unroll
    for (int j = 0; j < 8; ++j) h[j] = f2b(src[j]);
  } else {
#pragma unroll
    for (int j = 0; j < 8; ++j) h[j] = 0;
  }
  uint4 p;
  p.x = (unsigned)h[0] | ((unsigned)h[1] << 16);
  p.y = (unsigned)h[2] | ((unsigned)h[3] << 16);
  p.z = (unsigned)h[4] | ((unsigned)h[5] << 16);
  p.w = (unsigned)h[6] | ((unsigned)h[7] << 16);
  *(uint4*)(WP + (size_t)t * 8) = p;
}

// --- partial tril matvec over flat cols [LO, LO+272); i in {IT, IT+4, ...} -
template <int IT, int LO>
__device__ __forceinline__ void epi_partial2(const char* smem,
                                             const float* __restrict__ actions,
                                             const float* __restrict__ best,
                                             int grow, int lrow, float* pv) {
  float d[32];
  const float* ap = actions + (size_t)grow * 32;
  const float* bp = best + (size_t)grow * 32;
#pragma unroll
  for (int q = 0; q < 8; ++q) {
    float4 av = *(const float4*)(ap + q * 4);
    float4 bv = *(const float4*)(bp + q * 4);
    d[q * 4 + 0] = av.x - bv.x;
    d[q * 4 + 1] = av.y - bv.y;
    d[q * 4 + 2] = av.z - bv.z;
    d[q * 4 + 3] = av.w - bv.w;
  }
  const char* frow = smem + lrow * FL2_STRIDE;
  const int swz = (lrow & 7) << 4;
#pragma unroll
  for (int ii = 0; ii < 8; ++ii) {
    const int i = IT + ii * 4;                    // compile-time
    const int tri = (i * (i + 1)) >> 1;
    const int jlo = (LO > tri) ? (LO - tri) : 0;
    const int jhi = (i < LO + 271 - tri) ? i : (LO + 271 - tri);
    float vec = 0.f;
    if (jlo <= jhi) {                             // compile-time prune
      const int s0 = ((tri + jlo - LO) * 2) >> 4;
      const int s1 = ((tri + jhi - LO) * 2) >> 4;
#pragma unroll
      for (int s = s0; s <= s1; ++s) {
        uint4 w = *(const uint4*)(frow + ((s * 16) ^ swz));
        const unsigned* wp = (const unsigned*)&w;
#pragma unroll
        for (int e = 0; e < 8; ++e) {
          const int j = s * 8 + e + LO - tri;     // compile-time
          if (j < jlo || j > jhi) continue;
          unsigned short h = (e & 1) ? (unsigned short)(wp[e >> 1] >> 16)
                                     : (unsigned short)(wp[e >> 1] & 0xffffu);
          float v = b2f(h);
          if (j == i) vec += v * v * d[i];        // squared diagonal
          else        vec += v * d[j];
        }
      }
    }
    pv[ii] = vec;                                 // partial (NOT squared)
  }
}

// --- main fused kernel ------------------------------------------------------
__global__ void __launch_bounds__(256, 3)
adv_kernel(const float* __restrict__ logits,
           const float* __restrict__ best,
           const float* __restrict__ actions,
           const float* __restrict__ bvec,
           const unsigned short* __restrict__ WP,
           float* __restrict__ ws2) {
  extern __shared__ char smem[];
  const int tid = threadIdx.x;
  const int l   = tid & 63;
  const int wid = tid >> 6;                // 4 waves = 4 N-subcols of the half
  const int lr  = l & 15;
  const int lg  = l >> 4;
  const int c      = blockIdx.x & 1;       // column half: 0 -> cols 0..271
  const int brow   = (blockIdx.x >> 1) * 64;
  const int cstart = c * 17;               // first frag of this half
  const int startr = wid * 4;              // relative frag start (0,4,8,12)

  f32x4 acc[4][5];                         // 80 VGPRs
  {
    f32x4 zero = {0.f, 0.f, 0.f, 0.f};
#pragma unroll
    for (int m = 0; m < 4; ++m)
#pragma unroll
      for (int n = 0; n < 5; ++n) acc[m][n] = zero;
  }

  // A staging (round-4 path): thread stages frag m = wid, lane l:
  //   bf16(logits[brow+wid*16+lr][t*32 + lg*8 + 0..7]) -> abuf + tid*16
  const float* agbase = logits + (size_t)(brow + wid * 16 + lr) * 512 + lg * 8;

#define STAGE_W(dst, ks)                                                        \
  {                                                                             \
    const char* sW = (const char*)WP + (size_t)(ks) * WK_BYTES +                \
                     (size_t)cstart * 1024;                                     \
    _Pragma("unroll")                                                           \
    for (int q = 0; q < 4; ++q) {                                               \
      int fr = wid + q * 4;                                                     \
      __builtin_amdgcn_global_load_lds(                                         \
          (AS1 unsigned int*)(sW + fr * 1024 + l * 16),                         \
          (AS3 unsigned int*)((dst) + fr * 1024 + l * 16), 16, 0, 0);           \
    }                                                                           \
    if (wid == 0)                                                               \
      __builtin_amdgcn_global_load_lds(                                         \
          (AS1 unsigned int*)(sW + 16 * 1024 + l * 16),                         \
          (AS3 unsigned int*)((dst) + 16 * 1024 + l * 16), 16, 0, 0);           \
  }

#define LOAD_A(dst, ks)                                                         \
  {                                                                             \
    const float* g = agbase + (ks) * 32;                                        \
    (dst)[0] = *(const float4*)(g);                                             \
    (dst)[1] = *(const float4*)(g + 4);                                         \
  }

#define WRITE_A(buf_idx, src)                                                   \
  {                                                                             \
    uint4 p;                                                                    \
    p.x = f2b((src)[0].x) | ((unsigned)f2b((src)[0].y) << 16);                  \
    p.y = f2b((src)[0].z) | ((unsigned)f2b((src)[0].w) << 16);                  \
    p.z = f2b((src)[1].x) | ((unsigned)f2b((src)[1].y) << 16);                  \
    p.w = f2b((src)[1].z) | ((unsigned)f2b((src)[1].w) << 16);                  \
    *(uint4*)(smem + AOFF + (buf_idx) * 4096 + tid * 16) = p;                   \
  }

#define COMPUTE(p)                                                              \
  {                                                                             \
    const char* ab = smem + AOFF + (p) * 4096;                                  \
    const char* wb = smem + (p) * WSTEP;                                        \
    bf16x8 a[4];                                                                \
    _Pragma("unroll")                                                           \
    for (int m = 0; m < 4; ++m)                                                 \
      a[m] = *(const bf16x8*)(ab + m * 1024 + l * 16);                          \
    _Pragma("unroll")                                                           \
    for (int n = 0; n < 5; ++n) {                                               \
      bf16x8 w = *(const bf16x8*)(wb + (startr + n) * 1024 + l * 16);           \
      _Pragma("unroll")                                                         \
      for (int m = 0; m < 4; ++m)                                               \
        acc[m][n] = __builtin_amdgcn_mfma_f32_16x16x32_bf16(a[m], w, acc[m][n], 0, 0, 0); \
    }                                                                           \
  }

  float4 pf0[2], pf1[2];                 // distance-2 A prefetch (16 regs)
  LOAD_A(pf0, 0)
  LOAD_A(pf1, 1)
  STAGE_W(smem, 0)
  WRITE_A(0, pf0)
  __syncthreads();

  for (int t2 = 0; t2 < 16; t2 += 2) {
    // even step t = t2 (parity 0)
    if (t2 < 15) STAGE_W(smem + WSTEP, t2 + 1)
    if (t2 < 14) LOAD_A(pf0, t2 + 2)     // pf0 consumed two steps ago
    COMPUTE(0)
    if (t2 < 15) WRITE_A(1, pf1)         // compiler waits oldest A loads
    __syncthreads();
    // odd step t = t2+1 (parity 1)
    {
      const int t = t2 + 1;
      if (t < 15) STAGE_W(smem, t + 1)
      if (t < 14) LOAD_A(pf1, t + 2)
      COMPUTE(1)
      if (t < 15) WRITE_A(0, pf0)
      __syncthreads();
    }
  }

  // ---- flat-half(+bias) -> swizzled bf16 LDS [64][FL2_STRIDE] --------------
#pragma unroll
  for (int n = 0; n < 5; ++n) {
    int f_rel = (startr + n) * 16 + lr;    // < 272 always
    int f_abs = c * 272 + f_rel;
    if (f_abs < 528) {                     // frag 33 (pad) skipped
      float bb = bvec[f_abs];
#pragma unroll
      for (int m = 0; m < 4; ++m)
#pragma unroll
        for (int r = 0; r < 4; ++r) {
          int row = m * 16 + lg * 4 + r;   // C/D: col=lane&15, row=(lane>>4)*4+reg
          int byte = row * FL2_STRIDE + ((f_rel * 2) ^ ((row & 7) << 4));
          *(unsigned short*)(smem + byte) = f2b(acc[m][n][r] + bb);
        }
    }
  }
  __syncthreads();

  // ---- partial tril matvec: 4 thr/row, i = it + 4*ii; store to ws ----------
  {
    int it  = tid & 3;
    int lrow = tid >> 2;
    int grow = brow + lrow;
    float pv[8];
    if (c == 0) {
      switch (it) {
        case 0:  epi_partial2<0, 0>(smem, actions, best, grow, lrow, pv); break;
        case 1:  epi_partial2<1, 0>(smem, actions, best, grow, lrow, pv); break;
        case 2:  epi_partial2<2, 0>(smem, actions, best, grow, lrow, pv); break;
        default: epi_partial2<3, 0>(smem, actions, best, grow, lrow, pv); break;
      }
    } else {
      switch (it) {
        case 0:  epi_partial2<0, 272>(smem, actions, best, grow, lrow, pv); break;
        case 1:  epi_partial2<1, 272>(smem, actions, best, grow, lrow, pv); break;
        case 2:  epi_partial2<2, 272>(smem, actions, best, grow, lrow, pv); break;
        default: epi_partial2<3, 272>(smem, actions, best, grow, lrow, pv); break;
      }
    }
    float* wsp = ws2 + (size_t)grow * 64 + c * 32 + it * 8;
    float4 v0 = {pv[0], pv[1], pv[2], pv[3]};
    float4 v1 = {pv[4], pv[5], pv[6], pv[7]};
    *(float4*)(wsp)     = v0;
    *(float4*)(wsp + 4) = v1;
  }
}

// --- reduce: vec = half0 + half1; out = -0.5 * sum(vec^2) -------------------
__global__ void __launch_bounds__(256)
reduce_k(const float* __restrict__ ws2, float* __restrict__ out) {
  int row = blockIdx.x * 256 + threadIdx.x;
  const float* p = ws2 + (size_t)row * 64;
  float v[64];
#pragma unroll
  for (int q = 0; q < 16; ++q) {
    float4 x = *(const float4*)(p + q * 4);
    v[q * 4 + 0] = x.x; v[q * 4 + 1] = x.y; v[q * 4 + 2] = x.z; v[q * 4 + 3] = x.w;
  }
  float ssum = 0.f;
#pragma unroll
  for (int i = 0; i < 32; ++i) {
    int it = i & 3, ii = i >> 2;
    float vec = v[it * 8 + ii] + v[32 + it * 8 + ii];   // [c][it][ii]
    ssum += vec * vec;
  }
  out[row] = -0.5f * ssum;
}

extern "C" void kernel_launch(void* const* d_in, const int* in_sizes, int n_in,
                              void* d_out, int out_size, void* d_ws, size_t ws_size,
                              hipStream_t stream) {
  const float* logits  = (const float*)d_in[0];
  const float* best    = (const float*)d_in[1];
  const float* actions = (const float*)d_in[2];
  const float* W       = (const float*)d_in[3];
  const float* bvec    = (const float*)d_in[4];
  float* out = (float*)d_out;
  unsigned short* WP = (unsigned short*)d_ws;                 // 557056 B
  float* ws2 = (float*)((char*)d_ws + WS2_OFF);               // 65536*64*4 B

  hipLaunchKernelGGL(prep_wp, dim3(136), dim3(256), 0, stream, W, WP);
  int M = in_sizes[0] / 512;                                  // 65536 rows
  hipLaunchKernelGGL(adv_kernel, dim3((M / 64) * 2), dim3(256), SMEM_BYTES,
                     stream, logits, best, actions, bvec, WP, ws2);
  hipLaunchKernelGGL(reduce_k, dim3(M / 256), dim3(256), 0, stream, ws2, out);
}